// Round 4
// baseline (2104.642 us; speedup 1.0000x reference)
//
#include <hip/hip_runtime.h>
#include <hip/hip_bf16.h>

#define NN 100000
#define NE 100000
#define NCNT (14 * NN)
#define LP 136    // padded LDS pitch (bf16) for encoder kernels
#define LP2 168   // pitch for K=160 (meta)
#define SCAN_CHUNK 4096
#define NSCB ((NCNT + SCAN_CHUNK - 1) / SCAN_CHUNK)

typedef __bf16 bf16;
typedef __bf16 bf16x8 __attribute__((ext_vector_type(8)));
typedef float  f32x4  __attribute__((ext_vector_type(4)));
typedef unsigned long long u64;

// ---------- generic helpers ----------

__device__ __forceinline__ void gl2lds16(const bf16* g, bf16* l) {
    __builtin_amdgcn_global_load_lds(
        (const __attribute__((address_space(1))) void*)g,
        (__attribute__((address_space(3))) void*)l, 16, 0, 0);
}

__device__ __forceinline__ void zacc8(f32x4 acc[8]) {
    f32x4 z = {0.f, 0.f, 0.f, 0.f};
#pragma unroll
    for (int n = 0; n < 8; ++n) acc[n] = z;
}

// per-wave GroupNorm(1) stats: wave holds 16 full rows; rows (lane>>4)*4+r
__device__ __forceinline__ void gnstats(const f32x4 acc[8], float mean[4], float rs[4]) {
    float s1[4], s2[4];
#pragma unroll
    for (int r = 0; r < 4; ++r) { s1[r] = 0.f; s2[r] = 0.f; }
#pragma unroll
    for (int n = 0; n < 8; ++n)
#pragma unroll
        for (int r = 0; r < 4; ++r) { float v = acc[n][r]; s1[r] += v; s2[r] += v * v; }
#pragma unroll
    for (int off = 1; off < 16; off <<= 1) {
#pragma unroll
        for (int r = 0; r < 4; ++r) {
            s1[r] += __shfl_xor(s1[r], off, 64);
            s2[r] += __shfl_xor(s2[r], off, 64);
        }
    }
#pragma unroll
    for (int r = 0; r < 4; ++r) {
        const float m = s1[r] * 0.0078125f;
        const float v = fmaxf(s2[r] * 0.0078125f - m * m, 0.f);
        mean[r] = m;
        rs[r] = rsqrtf(v + 1e-5f);
    }
}

// ---------- encoder-path helpers ----------

template<int PITCH, int COLS>
__device__ inline void stageWB(const bf16* __restrict__ Wg, bf16* Wl) {
    constexpr int NV = 128 * COLS / 8;
    for (int i = threadIdx.x; i < NV; i += 256) {
        const int e = i * 8;
        const int r = e / COLS, c = e % COLS;
        *(float4*)(&Wl[r * PITCH + c]) = ((const float4*)Wg)[i];
    }
}

template<int PITCH, int KSTEPS>
__device__ inline void mmaT(const bf16* Al, const bf16* Wl, int m0, int lane, f32x4 acc[8]) {
#pragma unroll
    for (int kk = 0; kk < KSTEPS; ++kk) {
        bf16x8 a = *(const bf16x8*)(&Al[(m0 + (lane & 15)) * PITCH + kk * 32 + (lane >> 4) * 8]);
#pragma unroll
        for (int n = 0; n < 8; ++n) {
            bf16x8 b = *(const bf16x8*)(&Wl[(n * 16 + (lane & 15)) * PITCH + kk * 32 + (lane >> 4) * 8]);
            acc[n] = __builtin_amdgcn_mfma_f32_16x16x32_bf16(a, b, acc[n], 0, 0, 0);
        }
    }
}

// ---------- k_round helpers ----------

// stage one 128x128 bf16 W into WLbase (rows of 256B, slot ^= (row&7) via pre-swizzled src)
// 4 waves x 8 instrs x 1KB = 32KB
__device__ __forceinline__ void stageW(const bf16* __restrict__ Wg, bf16* WLbase,
                                       int w, int lane) {
#pragma unroll
    for (int k = 0; k < 8; ++k) {
        const int R = (w * 8 + k) * 4 + (lane >> 4);
        const int sg = (lane & 15) ^ ((k & 1) * 4 + (lane >> 4));   // == (lane&15) ^ (R&7)
        gl2lds16(Wg + R * 128 + sg * 8, WLbase + (w * 8 + k) * 512);
    }
}

// B reads from swizzled W tile; two m-tiles share each B fragment
__device__ __forceinline__ void mmaW2(const bf16* B, const bf16x8 aA[4], const bf16x8 aB[4],
                                      int r, int h, int r7, f32x4 accA[8], f32x4 accB[8]) {
#pragma unroll
    for (int kk = 0; kk < 4; ++kk) {
        const int sl = ((kk * 4 + h) ^ r7) * 8;
#pragma unroll
        for (int n = 0; n < 8; ++n) {
            const bf16x8 b = *(const bf16x8*)(B + (n * 16 + r) * 128 + sl);
            accA[n] = __builtin_amdgcn_mfma_f32_16x16x32_bf16(aA[kk], b, accA[n], 0, 0, 0);
            accB[n] = __builtin_amdgcn_mfma_f32_16x16x32_bf16(aB[kk], b, accB[n], 0, 0, 0);
        }
    }
}

__device__ __forceinline__ void loadrow(bf16x8 e[4], const bf16* __restrict__ feat,
                                        int s, int h) {
    const bf16x8* q = (const bf16x8*)(feat + (size_t)s * 128 + h * 8);
    e[0] = q[0]; e[1] = q[4]; e[2] = q[8]; e[3] = q[12];
}

__device__ __forceinline__ void faccum(float ag[4][8], const bf16x8 e[4]) {
#pragma unroll
    for (int kk = 0; kk < 4; ++kk)
#pragma unroll
        for (int j = 0; j < 8; ++j) ag[kk][j] += (float)e[kk][j];
}

// ---------- weight conversion ----------

__global__ void k_cvt(const float* __restrict__ s, bf16* __restrict__ d, int n) {
    for (int i = blockIdx.x * 256 + threadIdx.x; i < n; i += gridDim.x * 256)
        d[i] = (bf16)s[i];
}

__global__ void k_cvt_meta(const float* __restrict__ s, bf16* __restrict__ d) {
    for (int i = blockIdx.x * 256 + threadIdx.x; i < 128 * 160; i += gridDim.x * 256) {
        const int r = i / 160, c = i % 160;
        d[i] = (bf16)(c < 132 ? s[r * 132 + c] : 0.f);
    }
}

// ---------- CSR build ----------

__global__ __launch_bounds__(256) void k_count(const int* __restrict__ idx,
                                               const int* __restrict__ mask,
                                               int* __restrict__ cnt) {
    __shared__ int lim[14];
    if (threadIdx.x < 14) lim[threadIdx.x] = min(mask[threadIdx.x], NE);
    __syncthreads();
    for (int i = blockIdx.x * 256 + threadIdx.x; i < 14 * NE; i += gridDim.x * 256) {
        const int e = i / 14, t = i - e * 14;
        if (e < lim[t]) atomicAdd(&cnt[t * NN + idx[(size_t)e * 28 + 2 * t]], 1);
    }
}

__global__ __launch_bounds__(256) void k_scanA(const int* __restrict__ cnt,
                                               int* __restrict__ ptr,
                                               int* __restrict__ tot) {
    __shared__ int sm[256];
    const int tid = threadIdx.x;
    const int base = blockIdx.x * SCAN_CHUNK + tid * 16;
    int v[16]; int run = 0;
#pragma unroll
    for (int j = 0; j < 16; ++j) {
        const int x = (base + j < NCNT) ? cnt[base + j] : 0;
        v[j] = run; run += x;
    }
    sm[tid] = run; __syncthreads();
    for (int d = 1; d < 256; d <<= 1) {
        int t = 0;
        if (tid >= d) t = sm[tid - d];
        __syncthreads();
        sm[tid] += t;
        __syncthreads();
    }
    const int off = sm[tid] - run;
#pragma unroll
    for (int j = 0; j < 16; ++j)
        if (base + j < NCNT) ptr[base + j] = v[j] + off;
    if (tid == 255) tot[blockIdx.x] = sm[255];
}

__global__ void k_scanB(int* __restrict__ tot) {
    if (threadIdx.x == 0 && blockIdx.x == 0) {
        int acc = 0;
        for (int b = 0; b < NSCB; ++b) { const int t = tot[b]; tot[b] = acc; acc += t; }
        tot[NSCB] = acc;
    }
}

__global__ __launch_bounds__(256) void k_scanC(int* __restrict__ ptr,
                                               int* __restrict__ cursor,
                                               const int* __restrict__ tot) {
    const int base = blockIdx.x * SCAN_CHUNK;
    const int o = tot[blockIdx.x];
    for (int j = threadIdx.x; j < SCAN_CHUNK; j += 256) {
        const int i = base + j;
        if (i < NCNT) { const int p = ptr[i] + o; ptr[i] = p; cursor[i] = p; }
    }
    if (blockIdx.x == 0 && threadIdx.x == 0) ptr[NCNT] = tot[NSCB];
}

// elist entry: (edge_id << 32) | src  -> sortable by edge id, src in low word
__global__ __launch_bounds__(256) void k_fill(const int* __restrict__ idx,
                                              const int* __restrict__ mask,
                                              int* __restrict__ cursor,
                                              u64* __restrict__ el) {
    __shared__ int lim[14];
    if (threadIdx.x < 14) lim[threadIdx.x] = min(mask[threadIdx.x], NE);
    __syncthreads();
    for (int i = blockIdx.x * 256 + threadIdx.x; i < 14 * NE; i += gridDim.x * 256) {
        const int e = i / 14, t = i - e * 14;
        if (e < lim[t]) {
            const int dst = idx[(size_t)e * 28 + 2 * t];
            const int src = idx[(size_t)e * 28 + 2 * t + 1];
            const int pos = atomicAdd(&cursor[t * NN + dst], 1);
            el[pos] = ((u64)(unsigned)e << 32) | (unsigned)src;
        }
    }
}

__global__ __launch_bounds__(256) void k_sortseg(const int* __restrict__ ptr,
                                                 u64* __restrict__ el) {
    for (int i = blockIdx.x * 256 + threadIdx.x; i < NCNT; i += gridDim.x * 256) {
        const int s = ptr[i], e2 = ptr[i + 1];
        for (int a = s + 1; a < e2; ++a) {
            const u64 key = el[a];
            int b = a - 1;
            while (b >= s && el[b] > key) { el[b + 1] = el[b]; --b; }
            el[b + 1] = key;
        }
    }
}

// ---------- input encoder ----------

__global__ __launch_bounds__(256) void k_in(
    const float* __restrict__ nodes,
    const float* __restrict__ in1W, const float* __restrict__ in1b,
    const bf16* __restrict__ wIn2,
    const float* __restrict__ ing, const float* __restrict__ inbg,
    const float* __restrict__ seg1W, const float* __restrict__ seg1b,
    const bf16* __restrict__ wSeg2,
    const float* __restrict__ segg, const float* __restrict__ segbg,
    bf16* __restrict__ outPre)
{
    __shared__ __align__(16) bf16 Wl[128 * LP];
    __shared__ __align__(16) bf16 Al[64 * LP];
    __shared__ float w0[128], w1[128], bb[128];
    __shared__ float xs[64][4];
    const int tid = threadIdx.x;
    const int row0 = blockIdx.x * 64;
    if (tid < 64) {
        const int row = row0 + tid;
        float4 x = {0.f, 0.f, 0.f, 0.f};
        if (row < NN) x = *(const float4*)(nodes + (size_t)row * 8);
        xs[tid][0] = x.x; xs[tid][1] = x.y; xs[tid][2] = x.z; xs[tid][3] = x.w;
    }
    if (tid < 128) { w0[tid] = in1W[tid * 2]; w1[tid] = in1W[tid * 2 + 1]; bb[tid] = in1b[tid]; }
    stageWB<LP, 128>(wIn2, Wl);
    __syncthreads();
    for (int i = tid; i < 64 * 128; i += 256) {
        const int r = i >> 7, j = i & 127;
        Al[r * LP + j] = (bf16)fmaxf(xs[r][0] * w0[j] + xs[r][1] * w1[j] + bb[j], 0.f);
    }
    __syncthreads();
    const int lane = tid & 63, m0 = (tid >> 6) * 16;
    f32x4 accP[8]; zacc8(accP);
    mmaT<LP, 4>(Al, Wl, m0, lane, accP);
    __syncthreads();
    if (tid < 128) { w0[tid] = seg1W[tid * 2]; w1[tid] = seg1W[tid * 2 + 1]; bb[tid] = seg1b[tid]; }
    stageWB<LP, 128>(wSeg2, Wl);
    __syncthreads();
    for (int i = tid; i < 64 * 128; i += 256) {
        const int r = i >> 7, j = i & 127;
        Al[r * LP + j] = (bf16)fmaxf(xs[r][2] * w0[j] + xs[r][3] * w1[j] + bb[j], 0.f);
    }
    __syncthreads();
    f32x4 accQ[8]; zacc8(accQ);
    mmaT<LP, 4>(Al, Wl, m0, lane, accQ);

    float mP[4], rP[4], mQ[4], rQ[4];
    gnstats(accP, mP, rP);
    gnstats(accQ, mQ, rQ);
    float gP[8], bP[8], gQ[8], bQ[8];
#pragma unroll
    for (int n = 0; n < 8; ++n) {
        const int c = n * 16 + (lane & 15);
        gP[n] = ing[c]; bP[n] = inbg[c]; gQ[n] = segg[c]; bQ[n] = segbg[c];
    }
#pragma unroll
    for (int r = 0; r < 4; ++r) {
        const int row = row0 + m0 + (lane >> 4) * 4 + r;
        if (row < NN) {
#pragma unroll
            for (int n = 0; n < 8; ++n) {
                const float yp = (accP[n][r] - mP[r]) * rP[r] * gP[n] + bP[n];
                const float yq = (accQ[n][r] - mQ[r]) * rQ[r] * gQ[n] + bQ[n];
                outPre[(size_t)row * 128 + n * 16 + (lane & 15)] = (bf16)fmaxf(yp + yq, 0.f);
            }
        }
    }
}

// ---------- meta ----------

__global__ __launch_bounds__(256) void k_meta(
    const bf16* __restrict__ Apre, const float* __restrict__ nodes,
    const bf16* __restrict__ Wg,
    const float* __restrict__ g, const float* __restrict__ bg,
    float* __restrict__ featF, bf16* __restrict__ featB)
{
    __shared__ __align__(16) bf16 Wl[128 * LP2];
    __shared__ __align__(16) bf16 Al[64 * LP2];
    const int row0 = blockIdx.x * 64;
    stageWB<LP2, 160>(Wg, Wl);
    {
        const int r = threadIdx.x >> 2, q = threadIdx.x & 3;
        float4* d = (float4*)(&Al[r * LP2 + q * 32]);
        const int row = row0 + r;
        if (row < NN) {
            const float4* s = (const float4*)(Apre + (size_t)row * 128 + q * 32);
            float4 a0 = s[0], a1 = s[1], a2 = s[2], a3 = s[3];
            d[0] = a0; d[1] = a1; d[2] = a2; d[3] = a3;
        } else {
            float4 z = {0.f, 0.f, 0.f, 0.f};
            d[0] = z; d[1] = z; d[2] = z; d[3] = z;
        }
    }
    if (threadIdx.x < 64) {
        const int rr = threadIdx.x, row = row0 + rr;
        bf16* d = &Al[rr * LP2 + 128];
        if (row < NN) {
            const float4 x = *(const float4*)(nodes + (size_t)row * 8 + 4);
            d[0] = (bf16)x.x; d[1] = (bf16)x.y; d[2] = (bf16)x.z; d[3] = (bf16)x.w;
        } else {
            d[0] = (bf16)0.f; d[1] = (bf16)0.f; d[2] = (bf16)0.f; d[3] = (bf16)0.f;
        }
#pragma unroll
        for (int c = 4; c < 32; ++c) d[c] = (bf16)0.f;
    }
    __syncthreads();
    const int lane = threadIdx.x & 63, m0 = (threadIdx.x >> 6) * 16;
    f32x4 acc[8]; zacc8(acc);
    mmaT<LP2, 5>(Al, Wl, m0, lane, acc);

    float mean[4], rs[4];
    gnstats(acc, mean, rs);
    float gv[8], bv[8];
#pragma unroll
    for (int n = 0; n < 8; ++n) { const int c = n * 16 + (lane & 15); gv[n] = g[c]; bv[n] = bg[c]; }
#pragma unroll
    for (int r = 0; r < 4; ++r) {
        const int row = row0 + m0 + (lane >> 4) * 4 + r;
        if (row < NN) {
            const size_t off = (size_t)row * 128 + (lane & 15);
#pragma unroll
            for (int n = 0; n < 8; ++n) {
                const float y = (acc[n][r] - mean[r]) * rs[r] * gv[n] + bv[n];
                const float o = fmaxf(y, 0.f);
                featF[off + n * 16] = o;
                featB[off + n * 16] = (bf16)o;
            }
        }
    }
}

// ---------- fused round: 4 waves, 32 rows/wave, batched gather, 2-deep prefetch ----------

__global__ __launch_bounds__(256, 2) void k_round(
    const bf16* __restrict__ feat,
    const int* __restrict__ ptr,
    const int* __restrict__ sl32,      // u64 elist viewed as int pairs; src = sl32[2*j]
    const bf16* __restrict__ wEdgeR,
    const bf16* __restrict__ wCtrR,
    const bf16* __restrict__ wCtr2R,
    const float* __restrict__ ng, const float* __restrict__ nbg,
    const float* __restrict__ c2g, const float* __restrict__ c2bg,
    float* __restrict__ featF,
    bf16* __restrict__ featOut,
    float* __restrict__ outF,
    int last)
{
    __shared__ __align__(16) bf16 WL[2 * 16384];
    const int tid = threadIdx.x;
    const int w = tid >> 6, lane = tid & 63;
    const int r = lane & 15, h = lane >> 4, r7 = r & 7;
    const int row0 = blockIdx.x * 128;
    const int gA = row0 + w * 32 + r;          // two gather rows per lane
    const int gB = gA + 16;
    const bool okA = gA < NN, okB = gB < NN;

    stageW(wEdgeR, WL, w, lane);

    // phase-0 segment + srcs, phase-1 ptr
    int pA0 = 0, pA1 = 0, pB0 = 0, pB1 = 0;
    if (okA) { pA0 = ptr[gA]; pA1 = ptr[gA + 1]; }
    if (okB) { pB0 = ptr[gB]; pB1 = ptr[gB + 1]; }
    int sA0 = 0, sA1 = 0, sB0 = 0, sB1 = 0;
    if (pA1 > pA0)     sA0 = sl32[2 * pA0];
    if (pA1 > pA0 + 1) sA1 = sl32[2 * (pA0 + 1)];
    if (pB1 > pB0)     sB0 = sl32[2 * pB0];
    if (pB1 > pB0 + 1) sB1 = sl32[2 * (pB0 + 1)];
    int nA0 = 0, nA1 = 0, nB0 = 0, nB1 = 0;
    if (okA) { nA0 = ptr[NN + gA]; nA1 = ptr[NN + gA + 1]; }
    if (okB) { nB0 = ptr[NN + gB]; nB1 = ptr[NN + gB + 1]; }

    f32x4 accA[8], accB[8];
    zacc8(accA); zacc8(accB);

    for (int t = 0; t < 15; ++t) {
        bf16x8 afrA[4], afrB[4];
        if (t < 14) {
            // issue gather loads (batch 2 per row, both rows up front)
            bf16x8 eA0[4], eA1[4], eB0[4], eB1[4];
            const int dA = pA1 - pA0, dB = pB1 - pB0;
            if (dA > 0) loadrow(eA0, feat, sA0, h);
            if (dA > 1) loadrow(eA1, feat, sA1, h);
            if (dB > 0) loadrow(eB0, feat, sB0, h);
            if (dB > 1) loadrow(eB1, feat, sB1, h);
            // prefetch: slist for t+1 (ptr values ready), ptr for t+2
            int tsA0 = 0, tsA1 = 0, tsB0 = 0, tsB1 = 0;
            if (t < 13) {
                if (nA1 > nA0)     tsA0 = sl32[2 * nA0];
                if (nA1 > nA0 + 1) tsA1 = sl32[2 * (nA0 + 1)];
                if (nB1 > nB0)     tsB0 = sl32[2 * nB0];
                if (nB1 > nB0 + 1) tsB1 = sl32[2 * (nB0 + 1)];
            }
            int mA0 = 0, mA1 = 0, mB0 = 0, mB1 = 0;
            if (t < 12) {
                const size_t b2 = (size_t)(t + 2) * NN;
                if (okA) { mA0 = ptr[b2 + gA]; mA1 = ptr[b2 + gA + 1]; }
                if (okB) { mB0 = ptr[b2 + gB]; mB1 = ptr[b2 + gB + 1]; }
            }
            // accumulate (fixed order per lane -> deterministic)
            float ag[4][8];
#pragma unroll
            for (int kk = 0; kk < 4; ++kk)
#pragma unroll
                for (int j = 0; j < 8; ++j) ag[kk][j] = 0.f;
            if (dA > 0) faccum(ag, eA0);
            if (dA > 1) faccum(ag, eA1);
            for (int j = pA0 + 2; j < pA1; ++j) {
                bf16x8 e[4];
                loadrow(e, feat, sl32[2 * j], h);
                faccum(ag, e);
            }
#pragma unroll
            for (int kk = 0; kk < 4; ++kk)
#pragma unroll
                for (int j = 0; j < 8; ++j) afrA[kk][j] = (bf16)ag[kk][j];
#pragma unroll
            for (int kk = 0; kk < 4; ++kk)
#pragma unroll
                for (int j = 0; j < 8; ++j) ag[kk][j] = 0.f;
            if (dB > 0) faccum(ag, eB0);
            if (dB > 1) faccum(ag, eB1);
            for (int j = pB0 + 2; j < pB1; ++j) {
                bf16x8 e[4];
                loadrow(e, feat, sl32[2 * j], h);
                faccum(ag, e);
            }
#pragma unroll
            for (int kk = 0; kk < 4; ++kk)
#pragma unroll
                for (int j = 0; j < 8; ++j) afrB[kk][j] = (bf16)ag[kk][j];
            // rotate prefetch state
            pA0 = nA0; pA1 = nA1; pB0 = nB0; pB1 = nB1;
            sA0 = tsA0; sA1 = tsA1; sB0 = tsB0; sB1 = tsB1;
            nA0 = mA0; nA1 = mA1; nB0 = mB0; nB1 = mB1;
        } else {
            // ctr self-term: A = own feat row (already bf16)
            bf16x8 e[4];
            if (okA) { loadrow(e, feat, gA, h); } else { e[0]=e[1]=e[2]=e[3]=bf16x8{}; }
#pragma unroll
            for (int kk = 0; kk < 4; ++kk) afrA[kk] = e[kk];
            if (okB) { loadrow(e, feat, gB, h); } else { e[0]=e[1]=e[2]=e[3]=bf16x8{}; }
#pragma unroll
            for (int kk = 0; kk < 4; ++kk) afrB[kk] = e[kk];
        }
        if (!okA) { bf16x8 z{}; afrA[0]=afrA[1]=afrA[2]=afrA[3]=z; }
        if (!okB) { bf16x8 z{}; afrB[0]=afrB[1]=afrB[2]=afrB[3]=z; }

        asm volatile("s_waitcnt vmcnt(0)" ::: "memory");   // my gathers + my W[t] chunks landed
        __builtin_amdgcn_s_barrier();                      // all W[t] chunks in; MFMA[t-1] reads done
        __builtin_amdgcn_sched_barrier(0);
        if (t < 13)       stageW(wEdgeR + (size_t)(t + 1) * 16384, WL + ((t + 1) & 1) * 16384, w, lane);
        else if (t == 13) stageW(wCtrR,  WL,          w, lane);   // t=14 uses buf0
        else              stageW(wCtr2R, WL + 16384,  w, lane);   // ctr2 into buf1
        __builtin_amdgcn_sched_barrier(0);
        mmaW2(WL + (t & 1) * 16384, afrA, afrB, r, h, r7, accA, accB);
    }

    // epilogue 1: GN(norm) + relu -> swizzled bf16 A2 tile into buf0
    float meanA[4], rsA[4], meanB[4], rsB[4];
    gnstats(accA, meanA, rsA);
    gnstats(accB, meanB, rsB);
    float gv[8], bv[8];
#pragma unroll
    for (int n = 0; n < 8; ++n) { const int c = n * 16 + r; gv[n] = ng[c]; bv[n] = nbg[c]; }
    asm volatile("s_waitcnt vmcnt(0)" ::: "memory");   // ctr2 W landed (mine)
    __builtin_amdgcn_s_barrier();                      // all MFMA[14] reads of buf0 done
    __builtin_amdgcn_sched_barrier(0);
#pragma unroll
    for (int r2 = 0; r2 < 4; ++r2) {
        const int lrowA = w * 32 + h * 4 + r2;
        const int lrowB = lrowA + 16;
#pragma unroll
        for (int n = 0; n < 8; ++n) {
            const int col = n * 16 + r;
            const float yA = (accA[n][r2] - meanA[r2]) * rsA[r2] * gv[n] + bv[n];
            const float yB = (accB[n][r2] - meanB[r2]) * rsB[r2] * gv[n] + bv[n];
            const int slA = (col >> 3) ^ (lrowA & 7);
            const int slB = (col >> 3) ^ (lrowB & 7);
            *(bf16*)((char*)WL + lrowA * 256 + slA * 16 + (col & 7) * 2) = (bf16)fmaxf(yA, 0.f);
            *(bf16*)((char*)WL + lrowB * 256 + slB * 16 + (col & 7) * 2) = (bf16)fmaxf(yB, 0.f);
        }
    }
    asm volatile("s_waitcnt lgkmcnt(0)" ::: "memory");
    __builtin_amdgcn_s_barrier();
    __builtin_amdgcn_sched_barrier(0);

    // phase 2: ctr2 GEMM (A2 from buf0-swizzled, W from buf1)
    bf16x8 afrA2[4], afrB2[4];
    {
        const int arowA = w * 32 + r, arowB = arowA + 16;
#pragma unroll
        for (int kk = 0; kk < 4; ++kk) {
            const int slA = (kk * 4 + h) ^ (arowA & 7);
            const int slB = (kk * 4 + h) ^ (arowB & 7);
            afrA2[kk] = *(const bf16x8*)((const char*)WL + arowA * 256 + slA * 16);
            afrB2[kk] = *(const bf16x8*)((const char*)WL + arowB * 256 + slB * 16);
        }
    }
    zacc8(accA); zacc8(accB);
    mmaW2(WL + 16384, afrA2, afrB2, r, h, r7, accA, accB);

    // epilogue 2: GN(ctr2) + residual + relu
    gnstats(accA, meanA, rsA);
    gnstats(accB, meanB, rsB);
#pragma unroll
    for (int n = 0; n < 8; ++n) { const int c = n * 16 + r; gv[n] = c2g[c]; bv[n] = c2bg[c]; }
#pragma unroll
    for (int mi = 0; mi < 2; ++mi) {
        const f32x4* acc = mi ? accB : accA;
        const float* mean = mi ? meanB : meanA;
        const float* rsv = mi ? rsB : rsA;
#pragma unroll
        for (int r2 = 0; r2 < 4; ++r2) {
            const int orow = row0 + w * 32 + mi * 16 + h * 4 + r2;
            if (orow < NN) {
                const size_t off = (size_t)orow * 128 + r;
#pragma unroll
                for (int n = 0; n < 8; ++n) {
                    const float y = (acc[n][r2] - mean[r2]) * rsv[r2] * gv[n] + bv[n];
                    const float o = fmaxf(y + featF[off + n * 16], 0.f);
                    if (last) {
                        outF[off + n * 16] = o;
                    } else {
                        featF[off + n * 16] = o;
                        featOut[off + n * 16] = (bf16)o;
                    }
                }
            }
        }
    }
}

// ---------- nodes slice of the output ----------

__global__ void k_nodes(const float* __restrict__ nodes, float* __restrict__ out) {
    const int j = blockIdx.x * 256 + threadIdx.x;
    if (j < 2 * NN) out[(size_t)NN * 128 + j] = nodes[(size_t)(j >> 1) * 8 + (j & 1)];
}

// ---------- launch ----------

extern "C" void kernel_launch(void* const* d_in, const int* in_sizes, int n_in,
                              void* d_out, int out_size, void* d_ws, size_t ws_size,
                              hipStream_t stream) {
    const float* nodes  = (const float*)d_in[0];
    const int*   idx    = (const int*)d_in[1];
    const int*   mask   = (const int*)d_in[2];
    const float* in1W   = (const float*)d_in[3];
    const float* in1b   = (const float*)d_in[4];
    const float* in2W   = (const float*)d_in[5];
    const float* ing    = (const float*)d_in[6];
    const float* inbg   = (const float*)d_in[7];
    const float* seg1W  = (const float*)d_in[8];
    const float* seg1b  = (const float*)d_in[9];
    const float* seg2W  = (const float*)d_in[10];
    const float* segg   = (const float*)d_in[11];
    const float* segbg  = (const float*)d_in[12];
    const float* metaW  = (const float*)d_in[13];
    const float* metag  = (const float*)d_in[14];
    const float* metabg = (const float*)d_in[15];
    const float* ctrW   = (const float*)d_in[16];
    const float* edgeW  = (const float*)d_in[17];
    const float* normg  = (const float*)d_in[18];
    const float* normbg = (const float*)d_in[19];
    const float* ctr2W  = (const float*)d_in[20];
    const float* ctr2g  = (const float*)d_in[21];
    const float* ctr2bg = (const float*)d_in[22];
    float* out = (float*)d_out;

    char* w = (char*)d_ws;
    float* featF  = (float*)w; w += (size_t)NN * 128 * 4;
    bf16*  featB0 = (bf16*)w;  w += (size_t)NN * 128 * 2;
    bf16*  featB1 = (bf16*)w;  w += (size_t)NN * 128 * 2;
    bf16*  preB   = (bf16*)w;  w += (size_t)NN * 128 * 2;
    bf16*  wIn2   = (bf16*)w;  w += 16384 * 2;
    bf16*  wSeg2  = (bf16*)w;  w += 16384 * 2;
    bf16*  wMeta  = (bf16*)w;  w += 20480 * 2;
    bf16*  wCtr   = (bf16*)w;  w += 65536 * 2;
    bf16*  wCtr2  = (bf16*)w;  w += 65536 * 2;
    bf16*  wEdge  = (bf16*)w;  w += (size_t)917504 * 2;
    int*   cnt    = (int*)w;   w += (size_t)NCNT * 4;
    int*   ptr    = (int*)w;   w += ((size_t)NCNT + 4) * 4;
    int*   cursor = (int*)w;   w += (size_t)NCNT * 4;
    u64*   elist  = (u64*)w;   w += (size_t)14 * NE * 8 + 64;
    int*   tot    = (int*)w;   w += (NSCB + 1) * 4;

    dim3 blk(256);
    const int gRows = (NN + 63) / 64;

    // CSR build
    hipMemsetAsync(cnt, 0, (size_t)NCNT * 4, stream);
    k_count<<<2048, blk, 0, stream>>>(idx, mask, cnt);
    k_scanA<<<NSCB, blk, 0, stream>>>(cnt, ptr, tot);
    k_scanB<<<1, 64, 0, stream>>>(tot);
    k_scanC<<<NSCB, blk, 0, stream>>>(ptr, cursor, tot);
    k_fill<<<2048, blk, 0, stream>>>(idx, mask, cursor, elist);
    k_sortseg<<<2048, blk, 0, stream>>>(ptr, elist);

    // weights -> bf16
    k_cvt<<<64, blk, 0, stream>>>(in2W, wIn2, 16384);
    k_cvt<<<64, blk, 0, stream>>>(seg2W, wSeg2, 16384);
    k_cvt_meta<<<80, blk, 0, stream>>>(metaW, wMeta);
    k_cvt<<<256, blk, 0, stream>>>(ctrW, wCtr, 65536);
    k_cvt<<<256, blk, 0, stream>>>(ctr2W, wCtr2, 65536);
    k_cvt<<<2048, blk, 0, stream>>>(edgeW, wEdge, 917504);

    // encoders
    k_in<<<gRows, blk, 0, stream>>>(nodes, in1W, in1b, wIn2, ing, inbg,
                                    seg1W, seg1b, wSeg2, segg, segbg, preB);
    k_meta<<<gRows, blk, 0, stream>>>(preB, nodes, wMeta, metag, metabg, featF, featB0);

    // 4 rounds, ping-pong bf16 feat buffers; last round writes d_out directly
    bf16* bufs[2] = { featB0, featB1 };
    const int gR2 = (NN + 127) / 128;
    for (int i = 0; i < 4; ++i) {
        k_round<<<gR2, blk, 0, stream>>>(bufs[i & 1], ptr, (const int*)elist,
                                         wEdge + (size_t)i * 14 * 16384,
                                         wCtr + (size_t)i * 16384,
                                         wCtr2 + (size_t)i * 16384,
                                         normg + i * 128, normbg + i * 128,
                                         ctr2g + i * 128, ctr2bg + i * 128,
                                         featF, bufs[(i + 1) & 1], out,
                                         i == 3 ? 1 : 0);
    }
    k_nodes<<<(2 * NN + 255) / 256, blk, 0, stream>>>(nodes, out);
}

// Round 5
// 1491.492 us; speedup vs baseline: 1.4111x; 1.4111x over previous
//
#include <hip/hip_runtime.h>
#include <hip/hip_bf16.h>

#define NN 100000
#define NE 100000
#define NCNT (14 * NN)
#define LP 136    // padded LDS pitch (bf16) for encoder kernels
#define LP2 168   // pitch for K=160 (meta)
#define SCAN_CHUNK 4096
#define NSCB ((NCNT + SCAN_CHUNK - 1) / SCAN_CHUNK)

typedef __bf16 bf16;
typedef __bf16 bf16x8 __attribute__((ext_vector_type(8)));
typedef float  f32x4  __attribute__((ext_vector_type(4)));
typedef unsigned long long u64;

// ---------- generic helpers ----------

__device__ __forceinline__ void gl2lds16(const bf16* g, bf16* l) {
    __builtin_amdgcn_global_load_lds(
        (const __attribute__((address_space(1))) void*)g,
        (__attribute__((address_space(3))) void*)l, 16, 0, 0);
}

__device__ __forceinline__ void zacc8(f32x4 acc[8]) {
    f32x4 z = {0.f, 0.f, 0.f, 0.f};
#pragma unroll
    for (int n = 0; n < 8; ++n) acc[n] = z;
}

// per-wave GroupNorm(1) stats: wave holds 16 full rows; rows (lane>>4)*4+r
__device__ __forceinline__ void gnstats(const f32x4 acc[8], float mean[4], float rs[4]) {
    float s1[4], s2[4];
#pragma unroll
    for (int r = 0; r < 4; ++r) { s1[r] = 0.f; s2[r] = 0.f; }
#pragma unroll
    for (int n = 0; n < 8; ++n)
#pragma unroll
        for (int r = 0; r < 4; ++r) { float v = acc[n][r]; s1[r] += v; s2[r] += v * v; }
#pragma unroll
    for (int off = 1; off < 16; off <<= 1) {
#pragma unroll
        for (int r = 0; r < 4; ++r) {
            s1[r] += __shfl_xor(s1[r], off, 64);
            s2[r] += __shfl_xor(s2[r], off, 64);
        }
    }
#pragma unroll
    for (int r = 0; r < 4; ++r) {
        const float m = s1[r] * 0.0078125f;
        const float v = fmaxf(s2[r] * 0.0078125f - m * m, 0.f);
        mean[r] = m;
        rs[r] = rsqrtf(v + 1e-5f);
    }
}

// ---------- encoder-path helpers ----------

template<int PITCH, int COLS>
__device__ inline void stageWB(const bf16* __restrict__ Wg, bf16* Wl) {
    constexpr int NV = 128 * COLS / 8;
    for (int i = threadIdx.x; i < NV; i += 256) {
        const int e = i * 8;
        const int r = e / COLS, c = e % COLS;
        *(float4*)(&Wl[r * PITCH + c]) = ((const float4*)Wg)[i];
    }
}

template<int PITCH, int KSTEPS>
__device__ inline void mmaT(const bf16* Al, const bf16* Wl, int m0, int lane, f32x4 acc[8]) {
#pragma unroll
    for (int kk = 0; kk < KSTEPS; ++kk) {
        bf16x8 a = *(const bf16x8*)(&Al[(m0 + (lane & 15)) * PITCH + kk * 32 + (lane >> 4) * 8]);
#pragma unroll
        for (int n = 0; n < 8; ++n) {
            bf16x8 b = *(const bf16x8*)(&Wl[(n * 16 + (lane & 15)) * PITCH + kk * 32 + (lane >> 4) * 8]);
            acc[n] = __builtin_amdgcn_mfma_f32_16x16x32_bf16(a, b, acc[n], 0, 0, 0);
        }
    }
}

// ---------- k_round helpers (8-wave block, M=128) ----------

// stage one 128x128 bf16 W into WLbase (rows of 256B, slot ^= (row&7) via pre-swizzled src)
// 8 waves x 4 instrs x 1KB = 32KB
__device__ __forceinline__ void stageW(const bf16* __restrict__ Wg, bf16* WLbase,
                                       int w, int lane) {
#pragma unroll
    for (int k = 0; k < 4; ++k) {
        const int R = (w * 4 + k) * 4 + (lane >> 4);
        const int sg = (lane & 15) ^ ((k & 1) * 4 + (lane >> 4));   // == (lane&15) ^ (R&7)
        gl2lds16(Wg + R * 128 + sg * 8, WLbase + (w * 4 + k) * 512);
    }
}

// B-frag reads from swizzled W tile + MFMA
__device__ __forceinline__ void mmaW(const bf16* B, const bf16x8 afr[4],
                                     int r, int h, int r7, f32x4 acc[8]) {
#pragma unroll
    for (int kk = 0; kk < 4; ++kk) {
        const int sl = ((kk * 4 + h) ^ r7) * 8;
#pragma unroll
        for (int n = 0; n < 8; ++n) {
            const bf16x8 b = *(const bf16x8*)(B + (n * 16 + r) * 128 + sl);
            acc[n] = __builtin_amdgcn_mfma_f32_16x16x32_bf16(afr[kk], b, acc[n], 0, 0, 0);
        }
    }
}

__device__ __forceinline__ void loadrow(bf16x8 e[4], const bf16* __restrict__ feat,
                                        int s, int h) {
    const bf16x8* q = (const bf16x8*)(feat + (size_t)s * 128 + h * 8);
    e[0] = q[0]; e[1] = q[4]; e[2] = q[8]; e[3] = q[12];
}

__device__ __forceinline__ void faccum(float ag[4][8], const bf16x8 e[4]) {
#pragma unroll
    for (int kk = 0; kk < 4; ++kk)
#pragma unroll
        for (int j = 0; j < 8; ++j) ag[kk][j] += (float)e[kk][j];
}

// ---------- weight conversion (all weights, one kernel) ----------

__global__ __launch_bounds__(256) void k_cvt_all(
    const float* __restrict__ in2W, const float* __restrict__ seg2W,
    const float* __restrict__ metaW, const float* __restrict__ ctrW,
    const float* __restrict__ ctr2W, const float* __restrict__ edgeW,
    bf16* __restrict__ wIn2, bf16* __restrict__ wSeg2, bf16* __restrict__ wMeta,
    bf16* __restrict__ wCtr, bf16* __restrict__ wCtr2, bf16* __restrict__ wEdge)
{
    const int total = 16384 + 16384 + 20480 + 65536 + 65536 + 917504;
    for (int i = blockIdx.x * 256 + threadIdx.x; i < total; i += gridDim.x * 256) {
        int j = i;
        if (j < 16384) { wIn2[j] = (bf16)in2W[j]; continue; }
        j -= 16384;
        if (j < 16384) { wSeg2[j] = (bf16)seg2W[j]; continue; }
        j -= 16384;
        if (j < 20480) {
            const int r = j / 160, c = j % 160;
            wMeta[j] = (bf16)(c < 132 ? metaW[r * 132 + c] : 0.f);
            continue;
        }
        j -= 20480;
        if (j < 65536) { wCtr[j] = (bf16)ctrW[j]; continue; }
        j -= 65536;
        if (j < 65536) { wCtr2[j] = (bf16)ctr2W[j]; continue; }
        j -= 65536;
        wEdge[j] = (bf16)edgeW[j];
    }
}

// ---------- CSR build ----------

__global__ __launch_bounds__(256) void k_count(const int* __restrict__ idx,
                                               const int* __restrict__ mask,
                                               int* __restrict__ cnt) {
    __shared__ int lim[14];
    if (threadIdx.x < 14) lim[threadIdx.x] = min(mask[threadIdx.x], NE);
    __syncthreads();
    for (int i = blockIdx.x * 256 + threadIdx.x; i < 14 * NE; i += gridDim.x * 256) {
        const int e = i / 14, t = i - e * 14;
        if (e < lim[t]) atomicAdd(&cnt[t * NN + idx[(size_t)e * 28 + 2 * t]], 1);
    }
}

__global__ __launch_bounds__(256) void k_scanA(const int* __restrict__ cnt,
                                               int* __restrict__ ptr,
                                               int* __restrict__ tot) {
    __shared__ int sm[256];
    const int tid = threadIdx.x;
    const int base = blockIdx.x * SCAN_CHUNK + tid * 16;
    int v[16]; int run = 0;
#pragma unroll
    for (int j = 0; j < 16; ++j) {
        const int x = (base + j < NCNT) ? cnt[base + j] : 0;
        v[j] = run; run += x;
    }
    sm[tid] = run; __syncthreads();
    for (int d = 1; d < 256; d <<= 1) {
        int t = 0;
        if (tid >= d) t = sm[tid - d];
        __syncthreads();
        sm[tid] += t;
        __syncthreads();
    }
    const int off = sm[tid] - run;
#pragma unroll
    for (int j = 0; j < 16; ++j)
        if (base + j < NCNT) ptr[base + j] = v[j] + off;
    if (tid == 255) tot[blockIdx.x] = sm[255];
}

__global__ void k_scanB(int* __restrict__ tot) {
    if (threadIdx.x == 0 && blockIdx.x == 0) {
        int acc = 0;
        for (int b = 0; b < NSCB; ++b) { const int t = tot[b]; tot[b] = acc; acc += t; }
        tot[NSCB] = acc;
    }
}

__global__ __launch_bounds__(256) void k_scanC(int* __restrict__ ptr,
                                               int* __restrict__ cursor,
                                               const int* __restrict__ tot) {
    const int base = blockIdx.x * SCAN_CHUNK;
    const int o = tot[blockIdx.x];
    for (int j = threadIdx.x; j < SCAN_CHUNK; j += 256) {
        const int i = base + j;
        if (i < NCNT) { const int p = ptr[i] + o; ptr[i] = p; cursor[i] = p; }
    }
    if (blockIdx.x == 0 && threadIdx.x == 0) ptr[NCNT] = tot[NSCB];
}

// elist entry: (edge_id << 32) | src  -> sortable by edge id, src in low word
__global__ __launch_bounds__(256) void k_fill(const int* __restrict__ idx,
                                              const int* __restrict__ mask,
                                              int* __restrict__ cursor,
                                              u64* __restrict__ el) {
    __shared__ int lim[14];
    if (threadIdx.x < 14) lim[threadIdx.x] = min(mask[threadIdx.x], NE);
    __syncthreads();
    for (int i = blockIdx.x * 256 + threadIdx.x; i < 14 * NE; i += gridDim.x * 256) {
        const int e = i / 14, t = i - e * 14;
        if (e < lim[t]) {
            const int dst = idx[(size_t)e * 28 + 2 * t];
            const int src = idx[(size_t)e * 28 + 2 * t + 1];
            const int pos = atomicAdd(&cursor[t * NN + dst], 1);
            el[pos] = ((u64)(unsigned)e << 32) | (unsigned)src;
        }
    }
}

__global__ __launch_bounds__(256) void k_sortseg(const int* __restrict__ ptr,
                                                 u64* __restrict__ el) {
    for (int i = blockIdx.x * 256 + threadIdx.x; i < NCNT; i += gridDim.x * 256) {
        const int s = ptr[i], e2 = ptr[i + 1];
        for (int a = s + 1; a < e2; ++a) {
            const u64 key = el[a];
            int b = a - 1;
            while (b >= s && el[b] > key) { el[b + 1] = el[b]; --b; }
            el[b + 1] = key;
        }
    }
}

// ---------- input encoder ----------

__global__ __launch_bounds__(256) void k_in(
    const float* __restrict__ nodes,
    const float* __restrict__ in1W, const float* __restrict__ in1b,
    const bf16* __restrict__ wIn2,
    const float* __restrict__ ing, const float* __restrict__ inbg,
    const float* __restrict__ seg1W, const float* __restrict__ seg1b,
    const bf16* __restrict__ wSeg2,
    const float* __restrict__ segg, const float* __restrict__ segbg,
    bf16* __restrict__ outPre)
{
    __shared__ __align__(16) bf16 Wl[128 * LP];
    __shared__ __align__(16) bf16 Al[64 * LP];
    __shared__ float w0[128], w1[128], bb[128];
    __shared__ float xs[64][4];
    const int tid = threadIdx.x;
    const int row0 = blockIdx.x * 64;
    if (tid < 64) {
        const int row = row0 + tid;
        float4 x = {0.f, 0.f, 0.f, 0.f};
        if (row < NN) x = *(const float4*)(nodes + (size_t)row * 8);
        xs[tid][0] = x.x; xs[tid][1] = x.y; xs[tid][2] = x.z; xs[tid][3] = x.w;
    }
    if (tid < 128) { w0[tid] = in1W[tid * 2]; w1[tid] = in1W[tid * 2 + 1]; bb[tid] = in1b[tid]; }
    stageWB<LP, 128>(wIn2, Wl);
    __syncthreads();
    for (int i = tid; i < 64 * 128; i += 256) {
        const int r = i >> 7, j = i & 127;
        Al[r * LP + j] = (bf16)fmaxf(xs[r][0] * w0[j] + xs[r][1] * w1[j] + bb[j], 0.f);
    }
    __syncthreads();
    const int lane = tid & 63, m0 = (tid >> 6) * 16;
    f32x4 accP[8]; zacc8(accP);
    mmaT<LP, 4>(Al, Wl, m0, lane, accP);
    __syncthreads();
    if (tid < 128) { w0[tid] = seg1W[tid * 2]; w1[tid] = seg1W[tid * 2 + 1]; bb[tid] = seg1b[tid]; }
    stageWB<LP, 128>(wSeg2, Wl);
    __syncthreads();
    for (int i = tid; i < 64 * 128; i += 256) {
        const int r = i >> 7, j = i & 127;
        Al[r * LP + j] = (bf16)fmaxf(xs[r][2] * w0[j] + xs[r][3] * w1[j] + bb[j], 0.f);
    }
    __syncthreads();
    f32x4 accQ[8]; zacc8(accQ);
    mmaT<LP, 4>(Al, Wl, m0, lane, accQ);

    float mP[4], rP[4], mQ[4], rQ[4];
    gnstats(accP, mP, rP);
    gnstats(accQ, mQ, rQ);
    float gP[8], bP[8], gQ[8], bQ[8];
#pragma unroll
    for (int n = 0; n < 8; ++n) {
        const int c = n * 16 + (lane & 15);
        gP[n] = ing[c]; bP[n] = inbg[c]; gQ[n] = segg[c]; bQ[n] = segbg[c];
    }
#pragma unroll
    for (int r = 0; r < 4; ++r) {
        const int row = row0 + m0 + (lane >> 4) * 4 + r;
        if (row < NN) {
#pragma unroll
            for (int n = 0; n < 8; ++n) {
                const float yp = (accP[n][r] - mP[r]) * rP[r] * gP[n] + bP[n];
                const float yq = (accQ[n][r] - mQ[r]) * rQ[r] * gQ[n] + bQ[n];
                outPre[(size_t)row * 128 + n * 16 + (lane & 15)] = (bf16)fmaxf(yp + yq, 0.f);
            }
        }
    }
}

// ---------- meta ----------

__global__ __launch_bounds__(256) void k_meta(
    const bf16* __restrict__ Apre, const float* __restrict__ nodes,
    const bf16* __restrict__ Wg,
    const float* __restrict__ g, const float* __restrict__ bg,
    bf16* __restrict__ featB)
{
    __shared__ __align__(16) bf16 Wl[128 * LP2];
    __shared__ __align__(16) bf16 Al[64 * LP2];
    const int row0 = blockIdx.x * 64;
    stageWB<LP2, 160>(Wg, Wl);
    {
        const int r = threadIdx.x >> 2, q = threadIdx.x & 3;
        float4* d = (float4*)(&Al[r * LP2 + q * 32]);
        const int row = row0 + r;
        if (row < NN) {
            const float4* s = (const float4*)(Apre + (size_t)row * 128 + q * 32);
            float4 a0 = s[0], a1 = s[1], a2 = s[2], a3 = s[3];
            d[0] = a0; d[1] = a1; d[2] = a2; d[3] = a3;
        } else {
            float4 z = {0.f, 0.f, 0.f, 0.f};
            d[0] = z; d[1] = z; d[2] = z; d[3] = z;
        }
    }
    if (threadIdx.x < 64) {
        const int rr = threadIdx.x, row = row0 + rr;
        bf16* d = &Al[rr * LP2 + 128];
        if (row < NN) {
            const float4 x = *(const float4*)(nodes + (size_t)row * 8 + 4);
            d[0] = (bf16)x.x; d[1] = (bf16)x.y; d[2] = (bf16)x.z; d[3] = (bf16)x.w;
        } else {
            d[0] = (bf16)0.f; d[1] = (bf16)0.f; d[2] = (bf16)0.f; d[3] = (bf16)0.f;
        }
#pragma unroll
        for (int c = 4; c < 32; ++c) d[c] = (bf16)0.f;
    }
    __syncthreads();
    const int lane = threadIdx.x & 63, m0 = (threadIdx.x >> 6) * 16;
    f32x4 acc[8]; zacc8(acc);
    mmaT<LP2, 5>(Al, Wl, m0, lane, acc);

    float mean[4], rs[4];
    gnstats(acc, mean, rs);
    float gv[8], bv[8];
#pragma unroll
    for (int n = 0; n < 8; ++n) { const int c = n * 16 + (lane & 15); gv[n] = g[c]; bv[n] = bg[c]; }
#pragma unroll
    for (int r = 0; r < 4; ++r) {
        const int row = row0 + m0 + (lane >> 4) * 4 + r;
        if (row < NN) {
            const size_t off = (size_t)row * 128 + (lane & 15);
#pragma unroll
            for (int n = 0; n < 8; ++n) {
                const float y = (acc[n][r] - mean[r]) * rs[r] * gv[n] + bv[n];
                featB[off + n * 16] = (bf16)fmaxf(y, 0.f);
            }
        }
    }
}

// ---------- fused round: M=128, 512 threads, reg gather (4-idx prefetch, 2-deep rows) ----------

__global__ __launch_bounds__(512, 4) void k_round(
    const bf16* __restrict__ feat,
    const int* __restrict__ ptr,
    const int* __restrict__ sl32,      // u64 elist viewed as int pairs; src = sl32[2*j]
    const bf16* __restrict__ wEdgeR,
    const bf16* __restrict__ wCtrR,
    const bf16* __restrict__ wCtr2R,
    const float* __restrict__ ng, const float* __restrict__ nbg,
    const float* __restrict__ c2g, const float* __restrict__ c2bg,
    bf16* __restrict__ featOut,
    float* __restrict__ outF,
    int last)
{
    __shared__ __align__(16) bf16 WL[2 * 16384];
    const int tid = threadIdx.x;
    const int w = tid >> 6, lane = tid & 63;
    const int r = lane & 15, h = lane >> 4, r7 = r & 7;
    const int m0 = w * 16;
    const int row0 = blockIdx.x * 128;
    const int grow = row0 + m0 + r;            // row this lane gathers (A-side)
    const bool rowok = grow < NN;

    // prologue: async-stage W[0]
    stageW(wEdgeR, WL, w, lane);

    // phase-0 segment (up to 4 srcs prefetched) + phase-1 ptr
    int p0 = 0, p1 = 0;
    if (rowok) { p0 = ptr[grow]; p1 = ptr[grow + 1]; }
    int s0 = 0, s1 = 0, s2 = 0, s3 = 0;
    {
        const int d = p1 - p0;
        if (d > 0) s0 = sl32[2 * p0];
        if (d > 1) s1 = sl32[2 * (p0 + 1)];
        if (d > 2) s2 = sl32[2 * (p0 + 2)];
        if (d > 3) s3 = sl32[2 * (p0 + 3)];
    }
    int n0 = 0, n1 = 0;
    if (rowok) { n0 = ptr[NN + grow]; n1 = ptr[NN + grow + 1]; }

    f32x4 acc[8]; zacc8(acc);

    for (int t = 0; t < 15; ++t) {
        bf16x8 afr[4];
        if (t < 14) {
            const int d = p1 - p0;
            bf16x8 e0[4], e1[4];
            // first two rows: independent loads up front
            if (d > 0) loadrow(e0, feat, s0, h);
            if (d > 1) loadrow(e1, feat, s1, h);
            // prefetch for t+1 (srcs from n0/n1) and t+2 (ptr) — independent loads
            int u0 = 0, u1 = 0, u2 = 0, u3 = 0;
            if (t < 13) {
                const int dn = n1 - n0;
                if (dn > 0) u0 = sl32[2 * n0];
                if (dn > 1) u1 = sl32[2 * (n0 + 1)];
                if (dn > 2) u2 = sl32[2 * (n0 + 2)];
                if (dn > 3) u3 = sl32[2 * (n0 + 3)];
            }
            int q0 = 0, q1 = 0;
            if (t < 12 && rowok) {
                const size_t b2 = (size_t)(t + 2) * NN + grow;
                q0 = ptr[b2]; q1 = ptr[b2 + 1];
            }
            // accumulate, 2-deep pipelined; order s0,s1,s2,s3,tail (deterministic)
            float ag[4][8];
#pragma unroll
            for (int kk = 0; kk < 4; ++kk)
#pragma unroll
                for (int j = 0; j < 8; ++j) ag[kk][j] = 0.f;
            if (d > 0) faccum(ag, e0);
            if (d > 2) loadrow(e0, feat, s2, h);
            if (d > 1) faccum(ag, e1);
            if (d > 3) loadrow(e1, feat, s3, h);
            if (d > 2) faccum(ag, e0);
            if (d > 3) faccum(ag, e1);
            for (int j = p0 + 4; j < p1; ++j) {   // rare tail (deg>4)
                loadrow(e0, feat, sl32[2 * j], h);
                faccum(ag, e0);
            }
#pragma unroll
            for (int kk = 0; kk < 4; ++kk)
#pragma unroll
                for (int j = 0; j < 8; ++j) afr[kk][j] = (bf16)ag[kk][j];
            // rotate prefetch state
            p0 = n0; p1 = n1;
            s0 = u0; s1 = u1; s2 = u2; s3 = u3;
            n0 = q0; n1 = q1;
        } else {
            // ctr self-term: A = own feat row (already bf16)
            bf16x8 e0[4];
            if (rowok) loadrow(e0, feat, grow, h);
            else { bf16x8 z{}; e0[0] = e0[1] = e0[2] = e0[3] = z; }
#pragma unroll
            for (int kk = 0; kk < 4; ++kk) afr[kk] = e0[kk];
        }
        if (!rowok) { bf16x8 z{}; afr[0] = afr[1] = afr[2] = afr[3] = z; }

        asm volatile("s_waitcnt vmcnt(0)" ::: "memory");   // my gathers + my W[t] chunks landed
        __builtin_amdgcn_s_barrier();                      // all W[t] chunks in; MFMA[t-1] reads done
        __builtin_amdgcn_sched_barrier(0);
        if (t < 13)       stageW(wEdgeR + (size_t)(t + 1) * 16384, WL + ((t + 1) & 1) * 16384, w, lane);
        else if (t == 13) stageW(wCtrR,  WL,          w, lane);   // t=14 uses buf0
        else              stageW(wCtr2R, WL + 16384,  w, lane);   // ctr2 into buf1
        __builtin_amdgcn_sched_barrier(0);
        mmaW(WL + (t & 1) * 16384, afr, r, h, r7, acc);
    }

    // epilogue 1: GN(norm) + relu -> swizzled bf16 A2 tile in buf0
    float mean[4], rsv[4];
    gnstats(acc, mean, rsv);
    float gv[8], bv[8];
#pragma unroll
    for (int n = 0; n < 8; ++n) { const int c = n * 16 + r; gv[n] = ng[c]; bv[n] = nbg[c]; }
    asm volatile("s_waitcnt vmcnt(0)" ::: "memory");   // ctr2 W landed (mine)
    __builtin_amdgcn_s_barrier();                      // all MFMA[14] reads of buf0 done
    __builtin_amdgcn_sched_barrier(0);
#pragma unroll
    for (int r2 = 0; r2 < 4; ++r2) {
        const int lrow = m0 + h * 4 + r2;
#pragma unroll
        for (int n = 0; n < 8; ++n) {
            const float y = (acc[n][r2] - mean[r2]) * rsv[r2] * gv[n] + bv[n];
            const int col = n * 16 + r;
            const int slot = (col >> 3) ^ (lrow & 7);
            *(bf16*)((char*)WL + lrow * 256 + slot * 16 + (col & 7) * 2) = (bf16)fmaxf(y, 0.f);
        }
    }
    asm volatile("s_waitcnt lgkmcnt(0)" ::: "memory");
    __builtin_amdgcn_s_barrier();
    __builtin_amdgcn_sched_barrier(0);

    // phase 2: ctr2 GEMM (A2 from buf0-swizzled, W from buf1)
    bf16x8 afr2[4];
    {
        const int arow = m0 + r;
#pragma unroll
        for (int kk = 0; kk < 4; ++kk) {
            const int slot = (kk * 4 + h) ^ (arow & 7);
            afr2[kk] = *(const bf16x8*)((const char*)WL + arow * 256 + slot * 16);
        }
    }
    zacc8(acc);
    mmaW(WL + 16384, afr2, r, h, r7, acc);

    // epilogue 2: GN(ctr2) + residual(=feat, bf16) + relu
    gnstats(acc, mean, rsv);
#pragma unroll
    for (int n = 0; n < 8; ++n) { const int c = n * 16 + r; gv[n] = c2g[c]; bv[n] = c2bg[c]; }
#pragma unroll
    for (int r2 = 0; r2 < 4; ++r2) {
        const int orow = row0 + m0 + h * 4 + r2;
        if (orow < NN) {
            const size_t off = (size_t)orow * 128 + r;
            float res[8];
#pragma unroll
            for (int n = 0; n < 8; ++n) res[n] = (float)feat[off + n * 16];
#pragma unroll
            for (int n = 0; n < 8; ++n) {
                const float y = (acc[n][r2] - mean[r2]) * rsv[r2] * gv[n] + bv[n];
                const float o = fmaxf(y + res[n], 0.f);
                if (last) outF[off + n * 16] = o;
                else      featOut[off + n * 16] = (bf16)o;
            }
        }
    }
}

// ---------- nodes slice of the output ----------

__global__ void k_nodes(const float* __restrict__ nodes, float* __restrict__ out) {
    const int j = blockIdx.x * 256 + threadIdx.x;
    if (j < 2 * NN) out[(size_t)NN * 128 + j] = nodes[(size_t)(j >> 1) * 8 + (j & 1)];
}

// ---------- launch ----------

extern "C" void kernel_launch(void* const* d_in, const int* in_sizes, int n_in,
                              void* d_out, int out_size, void* d_ws, size_t ws_size,
                              hipStream_t stream) {
    const float* nodes  = (const float*)d_in[0];
    const int*   idx    = (const int*)d_in[1];
    const int*   mask   = (const int*)d_in[2];
    const float* in1W   = (const float*)d_in[3];
    const float* in1b   = (const float*)d_in[4];
    const float* in2W   = (const float*)d_in[5];
    const float* ing    = (const float*)d_in[6];
    const float* inbg   = (const float*)d_in[7];
    const float* seg1W  = (const float*)d_in[8];
    const float* seg1b  = (const float*)d_in[9];
    const float* seg2W  = (const float*)d_in[10];
    const float* segg   = (const float*)d_in[11];
    const float* segbg  = (const float*)d_in[12];
    const float* metaW  = (const float*)d_in[13];
    const float* metag  = (const float*)d_in[14];
    const float* metabg = (const float*)d_in[15];
    const float* ctrW   = (const float*)d_in[16];
    const float* edgeW  = (const float*)d_in[17];
    const float* normg  = (const float*)d_in[18];
    const float* normbg = (const float*)d_in[19];
    const float* ctr2W  = (const float*)d_in[20];
    const float* ctr2g  = (const float*)d_in[21];
    const float* ctr2bg = (const float*)d_in[22];
    float* out = (float*)d_out;

    char* w = (char*)d_ws;
    bf16*  featB0 = (bf16*)w;  w += (size_t)NN * 128 * 2;
    bf16*  featB1 = (bf16*)w;  w += (size_t)NN * 128 * 2;
    bf16*  preB   = (bf16*)w;  w += (size_t)NN * 128 * 2;
    bf16*  wIn2   = (bf16*)w;  w += 16384 * 2;
    bf16*  wSeg2  = (bf16*)w;  w += 16384 * 2;
    bf16*  wMeta  = (bf16*)w;  w += 20480 * 2;
    bf16*  wCtr   = (bf16*)w;  w += 65536 * 2;
    bf16*  wCtr2  = (bf16*)w;  w += 65536 * 2;
    bf16*  wEdge  = (bf16*)w;  w += (size_t)917504 * 2;
    int*   cnt    = (int*)w;   w += (size_t)NCNT * 4;
    int*   ptr    = (int*)w;   w += ((size_t)NCNT + 4) * 4;
    int*   cursor = (int*)w;   w += (size_t)NCNT * 4;
    u64*   elist  = (u64*)w;   w += (size_t)14 * NE * 8 + 64;
    int*   tot    = (int*)w;   w += (NSCB + 1) * 4;

    dim3 blk(256);
    const int gRows = (NN + 63) / 64;

    // CSR build
    hipMemsetAsync(cnt, 0, (size_t)NCNT * 4, stream);
    k_count<<<2048, blk, 0, stream>>>(idx, mask, cnt);
    k_scanA<<<NSCB, blk, 0, stream>>>(cnt, ptr, tot);
    k_scanB<<<1, 64, 0, stream>>>(tot);
    k_scanC<<<NSCB, blk, 0, stream>>>(ptr, cursor, tot);
    k_fill<<<2048, blk, 0, stream>>>(idx, mask, cursor, elist);
    k_sortseg<<<2048, blk, 0, stream>>>(ptr, elist);

    // weights -> bf16 (single kernel)
    k_cvt_all<<<1024, blk, 0, stream>>>(in2W, seg2W, metaW, ctrW, ctr2W, edgeW,
                                        wIn2, wSeg2, wMeta, wCtr, wCtr2, wEdge);

    // encoders
    k_in<<<gRows, blk, 0, stream>>>(nodes, in1W, in1b, wIn2, ing, inbg,
                                    seg1W, seg1b, wSeg2, segg, segbg, preB);
    k_meta<<<gRows, blk, 0, stream>>>(preB, nodes, wMeta, metag, metabg, featB0);

    // 4 rounds, ping-pong bf16 feat buffers; last round writes d_out directly
    bf16* bufs[2] = { featB0, featB1 };
    const int gR2 = (NN + 127) / 128;
    for (int i = 0; i < 4; ++i) {
        k_round<<<gR2, dim3(512), 0, stream>>>(bufs[i & 1], ptr, (const int*)elist,
                                               wEdge + (size_t)i * 14 * 16384,
                                               wCtr + (size_t)i * 16384,
                                               wCtr2 + (size_t)i * 16384,
                                               normg + i * 128, normbg + i * 128,
                                               ctr2g + i * 128, ctr2bg + i * 128,
                                               bufs[(i + 1) & 1], out,
                                               i == 3 ? 1 : 0);
    }
    k_nodes<<<(2 * NN + 255) / 256, blk, 0, stream>>>(nodes, out);
}